// Round 19
// baseline (900.595 us; speedup 1.0000x reference)
//
#include <hip/hip_runtime.h>
#include <hip/hip_fp16.h>

#define HID   300
#define NEIP  320            // nei row stride (f16), mult of 32
#define APB   4              // atoms per block in edge_csr
#define SWK(r) (((r) >> 1) & 3)   // 16B sub-chunk swizzle key within 64B tile

typedef _Float16 f16;
typedef f16  f16x2 __attribute__((ext_vector_type(2)));
typedef f16  f16x8 __attribute__((ext_vector_type(8)));
typedef float f32x4 __attribute__((ext_vector_type(4)));

// ---------------------------------------------------------------------------
// helpers
// ---------------------------------------------------------------------------
__device__ __forceinline__ f16x2 u2h(unsigned u) {
    union { unsigned u; f16x2 h; } c; c.u = u; return c.h;
}
__device__ __forceinline__ unsigned pk16(float a, float b) {
    union { f16 h[2]; unsigned u; } c; c.h[0] = (f16)a; c.h[1] = (f16)b;
    return c.u;
}
__device__ __forceinline__ void glds16(const void* g, void* l) {
    __builtin_amdgcn_global_load_lds(
        (const __attribute__((address_space(1))) void*)g,
        (__attribute__((address_space(3))) void*)l, 16, 0, 0);
}

// ---------------------------------------------------------------------------
__global__ __launch_bounds__(256) void fill_f32(float* __restrict__ p, int n, float v)
{
    int i = blockIdx.x * blockDim.x + threadIdx.x;
    int stride = gridDim.x * blockDim.x;
    for (; i < n; i += stride) p[i] = v;
}

__global__ __launch_bounds__(256) void zero_i32(int* __restrict__ p, int n)
{
    int i = blockIdx.x * blockDim.x + threadIdx.x;
    int stride = gridDim.x * blockDim.x;
    for (; i < n; i += stride) p[i] = 0;
}

// dst [dstRows][kpad] f16 zero-padded, 16B-sub-chunk-swizzled within each
// 64B k-tile (so a linear global_load_lds lands it pre-swizzled in LDS).
__global__ __launch_bounds__(256) void cvt_pad_f16(
    f16* __restrict__ dst, const float* __restrict__ src,
    int srcRows, int ldsrc, int kuse, int kpad, int dstRows)
{
    int i = blockIdx.x * 256 + threadIdx.x;
    const int total = dstRows * kpad;
    const int st = gridDim.x * 256;
    for (; i < total; i += st) {
        int r = i / kpad, k = i - r * kpad;
        float v = (r < srcRows && k < kuse) ? src[(size_t)r * ldsrc + k] : 0.f;
        const int t = k >> 5, kg = (k >> 3) & 3, w = k & 7;
        const int kd = (t << 5) | ((kg ^ SWK(r)) << 3) | w;
        dst[(size_t)r * kpad + kd] = (f16)v;
    }
}

// ---------------------------------------------------------------------------
// CSR build: histogram -> hierarchical scan -> scatter (+ ea permute to f16)
// ---------------------------------------------------------------------------
__global__ __launch_bounds__(256) void hist_tgt(
    const int* __restrict__ tgt, int* __restrict__ deg, int E, int N)
{
    int e = blockIdx.x * 256 + threadIdx.x;
    const int st = gridDim.x * 256;
    for (; e < E; e += st) {
        int t = tgt[e];
        t = ((unsigned)t < (unsigned)N) ? t : 0;
        atomicAdd(&deg[t], 1);
    }
}

__global__ __launch_bounds__(1024) void scan_p1(
    const int* __restrict__ deg, int* __restrict__ bsum, int N)
{
    __shared__ int s[1024];
    const int t = threadIdx.x;
    const int i = blockIdx.x * 1024 + t;
    s[t] = (i < N) ? deg[i] : 0;
    __syncthreads();
#pragma unroll
    for (int off = 512; off > 0; off >>= 1) {
        if (t < off) s[t] += s[t + off];
        __syncthreads();
    }
    if (t == 0) bsum[blockIdx.x] = s[0];
}

__global__ __launch_bounds__(1024) void scan_p2(
    const int* __restrict__ bsum, int* __restrict__ boff,
    int G, int* __restrict__ rowPtrN, int E)
{
    __shared__ int s[1024];
    const int t = threadIdx.x;
    s[t] = (t < G) ? bsum[t] : 0;
    __syncthreads();
    for (int off = 1; off < 1024; off <<= 1) {
        const int v = (t >= off) ? s[t - off] : 0;
        __syncthreads();
        s[t] += v;
        __syncthreads();
    }
    if (t < G) boff[t] = (t == 0) ? 0 : s[t - 1];
    if (t == 0) *rowPtrN = E;
}

__global__ __launch_bounds__(1024) void scan_p3(
    const int* __restrict__ deg, const int* __restrict__ boff,
    int* __restrict__ rowPtr, int* __restrict__ cursor, int N)
{
    __shared__ int s[1024];
    const int t = threadIdx.x;
    const int i = blockIdx.x * 1024 + t;
    const int v = (i < N) ? deg[i] : 0;
    s[t] = v;
    __syncthreads();
    for (int off = 1; off < 1024; off <<= 1) {
        const int w = (t >= off) ? s[t - off] : 0;
        __syncthreads();
        s[t] += w;
        __syncthreads();
    }
    if (i < N) {
        const int excl = boff[blockIdx.x] + s[t] - v;
        rowPtr[i] = excl;
        cursor[i] = excl;
    }
}

__global__ __launch_bounds__(256) void scatter_e(
    const int* __restrict__ src, const int* __restrict__ tgt,
    const float* __restrict__ ea,
    int* __restrict__ cursor, int* __restrict__ csrc,
    unsigned* __restrict__ eaPk,    // [E][7] u32 (14 f16)
    int E, int N)
{
    int e = blockIdx.x * 256 + threadIdx.x;
    const int st = gridDim.x * 256;
    for (; e < E; e += st) {
        int t = tgt[e];
        int s = src[e];
        t = ((unsigned)t < (unsigned)N) ? t : 0;
        s = ((unsigned)s < (unsigned)N) ? s : 0;
        const int p = atomicAdd(&cursor[t], 1);
        csrc[p] = s;
        const float* er = ea + (size_t)e * 14;
        unsigned* dst = eaPk + (size_t)p * 7;
#pragma unroll
        for (int k = 0; k < 7; ++k)
            dst[k] = pk16(er[2 * k], er[2 * k + 1]);
    }
}

// ---------------------------------------------------------------------------
// gemm_ns: BARRIER-FREE single-segment GEMM. The block's whole working set
// is LDS-resident: A-tile 64 x kpad (<=40KB) + a 160-col W chunk (<=100KB),
// staged in ONE prologue burst + ONE barrier; the K-loop is then pure
// ds_read_b128 + MFMA with zero synchronization (compiler fine-schedules
// lgkmcnt). Removes the per-step barrier/vmcnt drains that pinned every
// barriered variant (r11-r18) at ~1 TB/s.
// Block: 512 thr = 8 waves (4 rowgroups x 2 colgroups of 80), BM=64.
// blockIdx -> (row tile, chunk): chunk ch covers W rows [160*ch, 160*ch+160).
// LDS 140KB -> 1 block/CU. A f16 requires lda == kpad (true for nei).
// ---------------------------------------------------------------------------
__global__ __launch_bounds__(512) void gemm_ns(
    const void* __restrict__ A, int lda, int af16, int Kuse,
    const f16* __restrict__ W, int kpad,   // [320][kpad] pre-swizzled, padded
    const float* __restrict__ bias,
    f16* __restrict__ C, int ldc,
    int M, int do_relu)
{
    __shared__ f16 As[64 * 320];     // 40 KB max
    __shared__ f16 Ws[160 * 320];    // 100 KB max

    const int tid  = threadIdx.x;
    const int bm   = (blockIdx.x >> 1) * 64;
    const int cb   = (blockIdx.x & 1) * 160;
    const int lane = tid & 63;
    const int wv   = tid >> 6;           // 0..7
    const int rg   = wv >> 1;            // rowgroup 0..3 (16 rows each)
    const int cg   = wv & 1;             // colgroup 0..1 (80 cols each)
    const int lm   = lane & 15;
    const int kg   = lane >> 4;          // 16B sub-chunk of fragment

    const int nst = kpad >> 5;

    f32x4 acc[5];
#pragma unroll
    for (int c = 0; c < 5; ++c) acc[c] = (f32x4){0.f, 0.f, 0.f, 0.f};

    // ---- prologue: stage everything, one barrier ---------------------------
    if (af16) {
        // rows contiguous (lda == kpad, pre-swizzled): linear byte copy
        const int nch = (64 * kpad) >> 9;          // bytes/1024
        const char* base = (const char*)A + (size_t)bm * lda * 2;
        for (int c = wv; c < nch; c += 8)
            glds16(base + (c << 10) + lane * 16, (void*)&As[c << 9]);
    } else {
        const int cpr = kpad >> 3;                 // f16x8 chunks per row
        for (int idx = tid; idx < 64 * cpr; idx += 512) {
            const int row = idx / cpr;
            const int ks  = (idx - row * cpr) << 3;
            const int gmr = bm + row;
            f16x8 v = (f16x8){0, 0, 0, 0, 0, 0, 0, 0};
            if (gmr < M) {
                const float* p = (const float*)A + (size_t)gmr * lda + ks;
#pragma unroll
                for (int j = 0; j < 8; ++j)
                    v[j] = (ks + j < Kuse) ? (f16)p[j] : (f16)0.f;
            }
            const int t = ks >> 5, kgc = (ks >> 3) & 3;
            *(f16x8*)&As[row * kpad + (t << 5) + ((kgc ^ SWK(row)) << 3)] = v;
        }
    }
    {
        // W chunk rows [cb, cb+160): contiguous region, linear copy
        const int nch = (160 * kpad) >> 9;
        const char* base = (const char*)W + (size_t)cb * kpad * 2;
        for (int c = wv; c < nch; c += 8)
            glds16(base + (c << 10) + lane * 16, (void*)&Ws[c << 9]);
    }
    __syncthreads();

    // ---- barrier-free K-loop -----------------------------------------------
    for (int s = 0; s < nst; ++s) {
        const int R = (rg << 4) + lm;
        const f16x8 af = *(const f16x8*)
            &As[R * kpad + (s << 5) + ((kg ^ SWK(R)) << 3)];
        f16x8 bf[5];
#pragma unroll
        for (int c = 0; c < 5; ++c) {
            const int wr = cg * 80 + (c << 4) + lm;   // chunk-local row
            bf[c] = *(const f16x8*)
                &Ws[wr * kpad + (s << 5) + ((kg ^ SWK(wr)) << 3)];
        }
#pragma unroll
        for (int c = 0; c < 5; ++c)
            acc[c] = __builtin_amdgcn_mfma_f32_16x16x32_f16(
                af, bf[c], acc[c], 0, 0, 0);
    }

    // ---- epilogue: col = lane&15, row = 4*(lane>>4)+i ; only n<300 stored --
    const int gm0 = bm + (rg << 4) + ((lane >> 4) << 2);
#pragma unroll
    for (int c = 0; c < 5; ++c) {
        const int n = cb + cg * 80 + (c << 4) + lm;
        if (n >= HID) continue;
        const float bi = bias ? bias[n] : 0.f;
#pragma unroll
        for (int i = 0; i < 4; ++i) {
            const int gmo = gm0 + i;
            if (gmo >= M) continue;
            float v = acc[c][i] + bi;
            if (do_relu) v = fmaxf(v, 0.f);
            C[(size_t)gmo * ldc + n] = (f16)v;
        }
    }
}

// ---------------------------------------------------------------------------
// MFMA GEMM, K-resident A (r14 config) — kept for the two-segment W_o pass.
// ---------------------------------------------------------------------------
__global__ __launch_bounds__(512) void gemm_mfma(
    const void* __restrict__ A1, int lda1, int a1f16, int K1use,
    const f16* __restrict__ W1, int kpad1,
    const void* __restrict__ A2, int lda2, int a2f16, int K2use,
    const f16* __restrict__ W2, int kpad2,
    const float* __restrict__ bias,
    f16* __restrict__ C, int ldc,
    int M, int do_relu)
{
    __shared__ f16 As[64 * 320];    // 40 KB resident A (current segment)
    __shared__ f16 Ws[320 * 32];    // 20 KB W slice (single buffer)

    const int tid  = threadIdx.x;
    const int bm   = blockIdx.x * 64;
    const int lane = tid & 63;
    const int wv   = tid >> 6;          // 0..7
    const int wrow = (wv >> 2) * 32;    // 0 / 32
    const int wcol = (wv & 3) * 80;     // 0/80/160/240
    const int lm   = lane & 15;
    const int kg   = lane >> 4;

    const int n1 = A1 ? (kpad1 >> 5) : 0;
    const int n2 = A2 ? (kpad2 >> 5) : 0;
    const int ntot = n1 + n2;

    f32x4 acc[2][5];
#pragma unroll
    for (int r = 0; r < 2; ++r)
#pragma unroll
        for (int c = 0; c < 5; ++c) acc[r][c] = (f32x4){0.f, 0.f, 0.f, 0.f};

    auto stage_W = [&](int s) {
        const f16* W = (s < n1) ? W1 : W2;
        const int kpad = (s < n1) ? kpad1 : kpad2;
        const int k0 = (((s < n1) ? s : s - n1) << 5);
        const int r16 = lane >> 2;
        const int q   = lane & 3;
        for (int c = wv; c < 20; c += 8) {
            const int R = (c << 4) + r16;
            glds16((const char*)W + ((size_t)R * kpad + k0) * 2 + q * 16,
                   (void*)&Ws[c << 9]);
        }
    };

    auto stage_A = [&](int seg) {
        const void* A = seg ? A2 : A1;
        const int lda  = seg ? lda2 : lda1;
        const int af16 = seg ? a2f16 : a1f16;
        const int kuse = seg ? K2use : K1use;
        const int kpad = seg ? kpad2 : kpad1;
        if (af16) {
            const int nch = kpad >> 3;
            const char* base = (const char*)A + (size_t)bm * lda * 2;
            for (int c = wv; c < nch; c += 8)
                glds16(base + (c << 10) + lane * 16, (void*)&As[c << 9]);
        } else {
            const int cpr = kpad >> 3;
            for (int idx = tid; idx < 64 * cpr; idx += 512) {
                const int row = idx / cpr;
                const int ks  = (idx - row * cpr) << 3;
                const int gmr = bm + row;
                f16x8 v = (f16x8){0, 0, 0, 0, 0, 0, 0, 0};
                if (gmr < M) {
                    const float* p = (const float*)A + (size_t)gmr * lda + ks;
#pragma unroll
                    for (int j = 0; j < 8; ++j)
                        v[j] = (ks + j < kuse) ? (f16)p[j] : (f16)0.f;
                }
                const int t = ks >> 5, kgc = (ks >> 3) & 3;
                *(f16x8*)&As[row * kpad + (t << 5) + ((kgc ^ SWK(row)) << 3)] = v;
            }
        }
    };

    stage_A(0);
    stage_W(0);
    __syncthreads();

    for (int s = 0; s < ntot; ++s) {
        const int seg   = (s >= n1) ? 1 : 0;
        const int kpadA = seg ? kpad2 : kpad1;
        const int sl    = seg ? (s - n1) : s;
        f16x8 af[2], bf[5];
#pragma unroll
        for (int r = 0; r < 2; ++r) {
            const int R = wrow + (r << 4) + lm;
            af[r] = *(const f16x8*)&As[R * kpadA + (sl << 5) + ((kg ^ SWK(R)) << 3)];
        }
#pragma unroll
        for (int c = 0; c < 5; ++c) {
            const int R = wcol + (c << 4) + lm;
            bf[c] = *(const f16x8*)&Ws[R * 32 + ((kg ^ SWK(R)) << 3)];
        }
        __syncthreads();
        if (s + 1 < ntot) {
            stage_W(s + 1);
            if (s + 1 == n1 && n2) stage_A(1);
        }
#pragma unroll
        for (int r = 0; r < 2; ++r)
#pragma unroll
            for (int c = 0; c < 5; ++c)
                acc[r][c] = __builtin_amdgcn_mfma_f32_16x16x32_f16(
                    af[r], bf[c], acc[r][c], 0, 0, 0);
        __syncthreads();
    }

#pragma unroll
    for (int r = 0; r < 2; ++r) {
        const int gm0 = bm + wrow + (r << 4) + ((lane >> 4) << 2);
#pragma unroll
        for (int c = 0; c < 5; ++c) {
            const int n = wcol + (c << 4) + lm;
            if (n >= HID) continue;
            const float bi = bias ? bias[n] : 0.f;
#pragma unroll
            for (int i = 0; i < 4; ++i) {
                const int gmo = gm0 + i;
                if (gmo >= M) continue;
                float v = acc[r][c][i] + bi;
                if (do_relu) v = fmaxf(v, 0.f);
                C[(size_t)gmo * ldc + n] = (f16)v;
            }
        }
    }
}

// ---------------------------------------------------------------------------
// edge_csr: per target atom, accumulate messages of incoming edges in fp32
// registers, store one coalesced row (r18 config, unchanged).
// ---------------------------------------------------------------------------
template <int NSLOTS>
__global__ __launch_bounds__(192) void edge_csr(
    const unsigned* __restrict__ xa,      // [N][150] u32 pairs
    const unsigned* __restrict__ hn0,
    const unsigned* __restrict__ hn1,
    const int* __restrict__ rowPtr,
    const int* __restrict__ csrc,
    const unsigned* __restrict__ eaPk,    // [E][7] u32 (14 f16)
    const float* __restrict__ Wi,         // [300,147] fp32 (bond cols 133..146)
    unsigned* __restrict__ out,           // nei [N][160] u32, swizzled
    int N)
{
    const int p = threadIdx.x;
    f16x2 wpk[14];
    if (p < 150) {
#pragma unroll
        for (int k = 0; k < 14; ++k)
            wpk[k] = (f16x2){(f16)Wi[(2 * p) * 147 + 133 + k],
                             (f16)Wi[(2 * p + 1) * 147 + 133 + k]};
    }
    const f16x2 zero2 = (f16x2){(f16)0.f, (f16)0.f};

    const int a0 = blockIdx.x * APB;
    const int a1 = min(a0 + APB, N);
    for (int a = a0; a < a1; ++a) {
        const int beg = rowPtr[a];
        const int end = rowPtr[a + 1];
        float acc0 = 0.f, acc1 = 0.f;
        if (p < 150) {
#pragma unroll 2
            for (int j = beg; j < end; ++j) {
                const int s = __builtin_nontemporal_load(&csrc[j]);
                const size_t srow = (size_t)s * 150 + p;
                const unsigned u0 = xa[srow];
                unsigned u1 = 0, u2 = 0;
                if (NSLOTS > 1) u1 = hn0[srow];
                if (NSLOTS > 2) u2 = hn1[srow];
                const unsigned* eq = eaPk + (size_t)j * 7;
                f16x2 ebA = zero2, ebB = zero2;
#pragma unroll
                for (int k = 0; k < 7; ++k) {
                    const f16x2 e2 = u2h(__builtin_nontemporal_load(&eq[k]));
                    ebA += (f16x2){e2.x, e2.x} * wpk[2 * k];
                    ebB += (f16x2){e2.y, e2.y} * wpk[2 * k + 1];
                }
                f16x2 m = __builtin_elementwise_max(u2h(u0) + (ebA + ebB), zero2);
                if (NSLOTS > 1) m = __builtin_elementwise_max(m + u2h(u1), zero2);
                if (NSLOTS > 2) m = __builtin_elementwise_max(m + u2h(u2), zero2);
                acc0 += (float)m.x;
                acc1 += (float)m.y;
            }
        }
        if (p < NEIP / 2) {
            const unsigned val = (p < 150) ? pk16(acc0, acc1) : 0u;
            const int t = p >> 4, kgc = (p >> 2) & 3, w = p & 3;
            __builtin_nontemporal_store(val,
                &out[(size_t)a * (NEIP / 2) + (t << 4) + ((kgc ^ SWK(a)) << 2) + w]);
        }
    }
}

// ---------------------------------------------------------------------------
// mol_pool: mol[b,:300] = sum of atom_h rows (f16, stride 300) with batch==b
// ---------------------------------------------------------------------------
__global__ __launch_bounds__(256) void mol_pool(
    const f16* __restrict__ ah,       // [N][300] f16
    const int* __restrict__ batch,    // [N], sorted
    float* __restrict__ mol,          // [B,300]
    int N)
{
    const int b = blockIdx.x;
    int lo = 0, hi = N;
    while (lo < hi) { int mid = (lo + hi) >> 1; if (batch[mid] < b) lo = mid + 1; else hi = mid; }
    const int start = lo;
    hi = N;
    while (lo < hi) { int mid = (lo + hi) >> 1; if (batch[mid] < b + 1) lo = mid + 1; else hi = mid; }
    const int end = lo;

    for (int h = threadIdx.x; h < HID; h += 256) {
        float s = 0.f;
        for (int a = start; a < end; ++a) s += (float)ah[(size_t)a * HID + h];
        mol[(size_t)b * HID + h] = s;
    }
}

// ---------------------------------------------------------------------------
__global__ __launch_bounds__(64) void ffn2_k(
    const f16* __restrict__ h1,       // [B][300] f16
    const float* __restrict__ w2,     // [300]
    const float* __restrict__ b2, float* __restrict__ out, int B)
{
    const int b = blockIdx.x;
    float s = 0.f;
    for (int k = threadIdx.x; k < HID; k += 64)
        s += (float)h1[(size_t)b * HID + k] * w2[k];
#pragma unroll
    for (int off = 32; off > 0; off >>= 1) s += __shfl_down(s, off);
    if (threadIdx.x == 0) out[b] = s + b2[0];
}

// ---------------------------------------------------------------------------
extern "C" void kernel_launch(void* const* d_in, const int* in_sizes, int n_in,
                              void* d_out, int out_size, void* d_ws, size_t ws_size,
                              hipStream_t stream)
{
    float* outp = (float*)d_out;
    const int fillBlocks = (out_size + 255) / 256;

    if (n_in < 12) {
        fill_f32<<<fillBlocks, 256, 0, stream>>>(outp, out_size, 2.0e6f + n_in);
        return;
    }

    const int N = in_sizes[0] / 133;   // atoms
    const int E = in_sizes[1] / 2;     // edges
    const int B = out_size;            // molecules

    const long long expect[12] = {
        (long long)N * 133, (long long)E * 2, (long long)E * 14, N,
        300LL * 147, 300LL * 300, 300LL * 433, 300,
        300LL * 300, 300, 300, 1 };
    for (int i = 0; i < 12; ++i) {
        if ((long long)in_sizes[i] != expect[i]) {
            fill_f32<<<fillBlocks, 256, 0, stream>>>(outp, out_size,
                                                     3.0e6f + 1.0e4f * i);
            return;
        }
    }

    const int G = (N + 1023) / 1024;   // scan blocks (N=100K -> 98)
    if (G > 1024) {
        fill_f32<<<fillBlocks, 256, 0, stream>>>(outp, out_size, 4.0e6f);
        return;
    }

    // ---- workspace layout ---------------------------------------------------
    char* basep = (char*)d_ws;
    auto align16 = [](size_t v) { return (v + 15) & ~(size_t)15; };
    const size_t slotB  = align16((size_t)N * HID * sizeof(f16));    // 60 MB
    const size_t neiB   = align16((size_t)N * NEIP * sizeof(f16));   // 64 MB
    const size_t wSmall = align16(320 * 160 * sizeof(f16));
    const size_t wBig   = align16(320 * 320 * sizeof(f16));
    const size_t molB   = align16((size_t)B * HID * sizeof(float));
    const size_t h1B    = align16((size_t)B * HID * sizeof(f16));
    const size_t rpB    = align16((size_t)(N + 1) * sizeof(int));
    const size_t curB   = align16((size_t)N * sizeof(int));
    const size_t csrcB  = align16((size_t)E * sizeof(int));
    const size_t eaB    = align16((size_t)E * 7 * sizeof(unsigned));
    const size_t bsB    = align16(1024 * sizeof(int));
    const size_t need = 3 * slotB + neiB + 2 * wSmall + 3 * wBig
                      + molB + h1B + rpB + 2 * curB + csrcB + eaB + 2 * bsB;

    if (ws_size < need) {
        fill_f32<<<fillBlocks, 256, 0, stream>>>(outp, out_size,
                                                 (float)(ws_size >> 20));
        return;
    }

    const float* x     = (const float*)d_in[0];
    const int*   ei    = (const int*)d_in[1];
    const float* ea    = (const float*)d_in[2];
    const int*   batch = (const int*)d_in[3];
    const float* W_i   = (const float*)d_in[4];
    const float* W_h   = (const float*)d_in[5];
    const float* W_o   = (const float*)d_in[6];
    const float* W_ob  = (const float*)d_in[7];
    const float* f1w   = (const float*)d_in[8];
    const float* f1b   = (const float*)d_in[9];
    const float* f2w   = (const float*)d_in[10];
    const float* f2b   = (const float*)d_in[11];
    const int* src = ei;
    const int* tgt = ei + E;

    char* cp = basep;
    f16* xa     = (f16*)cp;         cp += slotB;   // later atom_h
    f16* hn0    = (f16*)cp;         cp += slotB;
    f16* hn1    = (f16*)cp;         cp += slotB;
    f16* nei    = (f16*)cp;         cp += neiB;
    f16* WiA    = (f16*)cp;         cp += wSmall;
    f16* Wh     = (f16*)cp;         cp += wBig;
    f16* WoA    = (f16*)cp;         cp += wSmall;
    f16* WoB    = (f16*)cp;         cp += wBig;
    f16* Wf1    = (f16*)cp;         cp += wBig;
    float* mol  = (float*)cp;       cp += molB;
    f16* h1     = (f16*)cp;         cp += h1B;
    int* rowPtr = (int*)cp;         cp += rpB;
    int* cursor = (int*)cp;         cp += curB;
    int* deg    = (int*)cp;         cp += curB;
    int* csrc   = (int*)cp;         cp += csrcB;
    unsigned* eaPk = (unsigned*)cp; cp += eaB;
    int* bsum   = (int*)cp;         cp += bsB;
    int* boff   = (int*)cp;         cp += bsB;

    const unsigned* xa_u  = (const unsigned*)xa;
    const unsigned* hn0_u = (const unsigned*)hn0;
    const unsigned* hn1_u = (const unsigned*)hn1;
    unsigned*       nei_u = (unsigned*)nei;

    const int gAtom   = (N + 63) / 64;         // r14 kernel grid (step 7)
    const int gAtomNS = ((N + 63) / 64) * 2;   // gemm_ns: x2 column chunks
    const int gMolNS  = ((B + 63) / 64) * 2;
    const int gEdge   = (N + APB - 1) / APB;

    // --- CSR build (+ permuted f16 bond features) ---
    zero_i32<<<128, 256, 0, stream>>>(deg, N);
    hist_tgt<<<1024, 256, 0, stream>>>(tgt, deg, E, N);
    scan_p1<<<G, 1024, 0, stream>>>(deg, bsum, N);
    scan_p2<<<1, 1024, 0, stream>>>(bsum, boff, G, rowPtr + N, E);
    scan_p3<<<G, 1024, 0, stream>>>(deg, boff, rowPtr, cursor, N);
    scatter_e<<<1024, 256, 0, stream>>>(src, tgt, ea, cursor, csrc, eaPk, E, N);

    // --- weights -> padded, pre-swizzled f16 ---
    cvt_pad_f16<<<64,  256, 0, stream>>>(WiA, W_i,       300, 147, 133, 160, 320);
    cvt_pad_f16<<<128, 256, 0, stream>>>(Wh,  W_h,       300, 300, 300, 320, 320);
    cvt_pad_f16<<<64,  256, 0, stream>>>(WoA, W_o,       300, 433, 133, 160, 320);
    cvt_pad_f16<<<128, 256, 0, stream>>>(WoB, W_o + 133, 300, 433, 300, 320, 320);
    cvt_pad_f16<<<128, 256, 0, stream>>>(Wf1, f1w,       300, 300, 300, 320, 320);

    // 1. xa = x @ W_i[:, :133]^T -> xa [N][300]   (barrier-free GEMM)
    gemm_ns<<<gAtomNS, 512, 0, stream>>>(x, 133, 0, 133, WiA, 160,
        nullptr, xa, HID, N, 0);
    // 2. nei0 = segsum(m0)
    edge_csr<1><<<gEdge, 192, 0, stream>>>(xa_u, hn0_u, hn1_u, rowPtr, csrc,
                                           eaPk, W_i, nei_u, N);
    // 3. hn0 = nei0 @ W_h^T   (barrier-free GEMM)
    gemm_ns<<<gAtomNS, 512, 0, stream>>>(nei, NEIP, 1, NEIP, Wh, 320,
        nullptr, hn0, HID, N, 0);
    // 4. nei1 = segsum(m1)
    edge_csr<2><<<gEdge, 192, 0, stream>>>(xa_u, hn0_u, hn1_u, rowPtr, csrc,
                                           eaPk, W_i, nei_u, N);
    // 5. hn1 = nei1 @ W_h^T   (barrier-free GEMM)
    gemm_ns<<<gAtomNS, 512, 0, stream>>>(nei, NEIP, 1, NEIP, Wh, 320,
        nullptr, hn1, HID, N, 0);
    // 6. atom_msg = segsum(m2)
    edge_csr<3><<<gEdge, 192, 0, stream>>>(xa_u, hn0_u, hn1_u, rowPtr, csrc,
                                           eaPk, W_i, nei_u, N);
    // 7. atom_h = relu(x @ WoA^T + msg @ WoB^T + b) -> xa buffer (dead)
    gemm_mfma<<<gAtom, 512, 0, stream>>>(x, 133, 0, 133, WoA, 160,
        nei, NEIP, 1, NEIP, WoB, 320, W_ob, xa, HID, N, 1);
    // 8. mol[b] = segment_sum(atom_h)
    mol_pool<<<B, 256, 0, stream>>>(xa, batch, mol, N);
    // 9. h1 = relu(mol @ ffn1^T + b1)   (barrier-free GEMM)
    gemm_ns<<<gMolNS, 512, 0, stream>>>(mol, 300, 0, 300, Wf1, 320,
        f1b, h1, HID, B, 1);
    // 10. out = h1 @ ffn2^T + b2
    ffn2_k<<<B, 64, 0, stream>>>(h1, f2w, f2b, outp, B);
}

// Round 20
// 771.886 us; speedup vs baseline: 1.1667x; 1.1667x over previous
//
#include <hip/hip_runtime.h>
#include <hip/hip_fp16.h>

#define HID   300
#define NEIP  320            // nei row stride (f16), mult of 32
#define APB   8              // atoms per block in edge_csr
#define SWK(r) (((r) >> 1) & 3)   // 16B sub-chunk swizzle key within 64B tile

typedef _Float16 f16;
typedef f16  f16x2 __attribute__((ext_vector_type(2)));
typedef f16  f16x8 __attribute__((ext_vector_type(8)));
typedef float f32x4 __attribute__((ext_vector_type(4)));

// ---------------------------------------------------------------------------
// helpers
// ---------------------------------------------------------------------------
__device__ __forceinline__ f16x2 u2h(unsigned u) {
    union { unsigned u; f16x2 h; } c; c.u = u; return c.h;
}
__device__ __forceinline__ unsigned pk16(float a, float b) {
    union { f16 h[2]; unsigned u; } c; c.h[0] = (f16)a; c.h[1] = (f16)b;
    return c.u;
}
__device__ __forceinline__ void glds16(const void* g, void* l) {
    __builtin_amdgcn_global_load_lds(
        (const __attribute__((address_space(1))) void*)g,
        (__attribute__((address_space(3))) void*)l, 16, 0, 0);
}

// ---------------------------------------------------------------------------
__global__ __launch_bounds__(256) void fill_f32(float* __restrict__ p, int n, float v)
{
    int i = blockIdx.x * blockDim.x + threadIdx.x;
    int stride = gridDim.x * blockDim.x;
    for (; i < n; i += stride) p[i] = v;
}

__global__ __launch_bounds__(256) void zero_i32(int* __restrict__ p, int n)
{
    int i = blockIdx.x * blockDim.x + threadIdx.x;
    int stride = gridDim.x * blockDim.x;
    for (; i < n; i += stride) p[i] = 0;
}

// dst [dstRows][kpad] f16 zero-padded, 16B-sub-chunk-swizzled within each
// 64B k-tile (so a linear global_load_lds lands it pre-swizzled in LDS).
__global__ __launch_bounds__(256) void cvt_pad_f16(
    f16* __restrict__ dst, const float* __restrict__ src,
    int srcRows, int ldsrc, int kuse, int kpad, int dstRows)
{
    int i = blockIdx.x * 256 + threadIdx.x;
    const int total = dstRows * kpad;
    const int st = gridDim.x * 256;
    for (; i < total; i += st) {
        int r = i / kpad, k = i - r * kpad;
        float v = (r < srcRows && k < kuse) ? src[(size_t)r * ldsrc + k] : 0.f;
        const int t = k >> 5, kg = (k >> 3) & 3, w = k & 7;
        const int kd = (t << 5) | ((kg ^ SWK(r)) << 3) | w;
        dst[(size_t)r * kpad + kd] = (f16)v;
    }
}

// ---------------------------------------------------------------------------
// CSR build: histogram -> hierarchical scan -> scatter (+ ea permute to f16)
// ---------------------------------------------------------------------------
__global__ __launch_bounds__(256) void hist_tgt(
    const int* __restrict__ tgt, int* __restrict__ deg, int E, int N)
{
    int e = blockIdx.x * 256 + threadIdx.x;
    const int st = gridDim.x * 256;
    for (; e < E; e += st) {
        int t = tgt[e];
        t = ((unsigned)t < (unsigned)N) ? t : 0;
        atomicAdd(&deg[t], 1);
    }
}

__global__ __launch_bounds__(1024) void scan_p1(
    const int* __restrict__ deg, int* __restrict__ bsum, int N)
{
    __shared__ int s[1024];
    const int t = threadIdx.x;
    const int i = blockIdx.x * 1024 + t;
    s[t] = (i < N) ? deg[i] : 0;
    __syncthreads();
#pragma unroll
    for (int off = 512; off > 0; off >>= 1) {
        if (t < off) s[t] += s[t + off];
        __syncthreads();
    }
    if (t == 0) bsum[blockIdx.x] = s[0];
}

__global__ __launch_bounds__(1024) void scan_p2(
    const int* __restrict__ bsum, int* __restrict__ boff,
    int G, int* __restrict__ rowPtrN, int E)
{
    __shared__ int s[1024];
    const int t = threadIdx.x;
    s[t] = (t < G) ? bsum[t] : 0;
    __syncthreads();
    for (int off = 1; off < 1024; off <<= 1) {
        const int v = (t >= off) ? s[t - off] : 0;
        __syncthreads();
        s[t] += v;
        __syncthreads();
    }
    if (t < G) boff[t] = (t == 0) ? 0 : s[t - 1];
    if (t == 0) *rowPtrN = E;
}

__global__ __launch_bounds__(1024) void scan_p3(
    const int* __restrict__ deg, const int* __restrict__ boff,
    int* __restrict__ rowPtr, int* __restrict__ cursor, int N)
{
    __shared__ int s[1024];
    const int t = threadIdx.x;
    const int i = blockIdx.x * 1024 + t;
    const int v = (i < N) ? deg[i] : 0;
    s[t] = v;
    __syncthreads();
    for (int off = 1; off < 1024; off <<= 1) {
        const int w = (t >= off) ? s[t - off] : 0;
        __syncthreads();
        s[t] += w;
        __syncthreads();
    }
    if (i < N) {
        const int excl = boff[blockIdx.x] + s[t] - v;
        rowPtr[i] = excl;
        cursor[i] = excl;
    }
}

__global__ __launch_bounds__(256) void scatter_e(
    const int* __restrict__ src, const int* __restrict__ tgt,
    const float* __restrict__ ea,
    int* __restrict__ cursor, int* __restrict__ csrc,
    unsigned* __restrict__ eaPk,    // [E][7] u32 (14 f16)
    int E, int N)
{
    int e = blockIdx.x * 256 + threadIdx.x;
    const int st = gridDim.x * 256;
    for (; e < E; e += st) {
        int t = tgt[e];
        int s = src[e];
        t = ((unsigned)t < (unsigned)N) ? t : 0;
        s = ((unsigned)s < (unsigned)N) ? s : 0;
        const int p = atomicAdd(&cursor[t], 1);
        csrc[p] = s;
        const float* er = ea + (size_t)e * 14;
        unsigned* dst = eaPk + (size_t)p * 7;
#pragma unroll
        for (int k = 0; k < 7; ++k)
            dst[k] = pk16(er[2 * k], er[2 * k + 1]);
    }
}

// ---------------------------------------------------------------------------
// MFMA GEMM, K-resident A + double-buffered W, ONE barrier per K-step:
// C = act( A1@W1^T + A2@W2^T + bias ), 300 out cols.
// A staged ONCE into LDS (glds burst for f16, reg-convert for fp32);
// W slice (320x32) staged per step into Ws[s&1], issued at the TOP of the
// step so the in-flight window covers frag ds_reads + 10 MFMAs (~2x r14's
// window) and is drained at the NEXT step's barrier. Barrier count halves.
// Extra barrier only at the two-segment boundary (A-restage race guard).
// Block: 512 thr = 8 waves (2 row x 4 col), BM=64, BK=32.
// LDS = 40KB A + 2x20KB W = 80KB -> 2 blocks/CU (same occupancy as r14).
// ---------------------------------------------------------------------------
__global__ __launch_bounds__(512) void gemm_mfma(
    const void* __restrict__ A1, int lda1, int a1f16, int K1use,
    const f16* __restrict__ W1, int kpad1,
    const void* __restrict__ A2, int lda2, int a2f16, int K2use,
    const f16* __restrict__ W2, int kpad2,
    const float* __restrict__ bias,
    f16* __restrict__ C, int ldc,
    int M, int do_relu)
{
    __shared__ f16 As[64 * 320];       // 40 KB resident A (current segment)
    __shared__ f16 Ws[2][320 * 32];    // 2 x 20 KB W slices

    const int tid  = threadIdx.x;
    const int bm   = blockIdx.x * 64;
    const int lane = tid & 63;
    const int wv   = tid >> 6;          // 0..7
    const int wrow = (wv >> 2) * 32;    // 0 / 32
    const int wcol = (wv & 3) * 80;     // 0/80/160/240
    const int lm   = lane & 15;
    const int kg   = lane >> 4;         // 16B sub-chunk of this lane's fragment

    const int n1 = A1 ? (kpad1 >> 5) : 0;
    const int n2 = A2 ? (kpad2 >> 5) : 0;
    const int ntot = n1 + n2;

    f32x4 acc[2][5];
#pragma unroll
    for (int r = 0; r < 2; ++r)
#pragma unroll
        for (int c = 0; c < 5; ++c) acc[r][c] = (f32x4){0.f, 0.f, 0.f, 0.f};

    auto stage_W = [&](int s, int b) {
        const f16* W = (s < n1) ? W1 : W2;
        const int kpad = (s < n1) ? kpad1 : kpad2;
        const int k0 = (((s < n1) ? s : s - n1) << 5);
        const int r16 = lane >> 2;
        const int q   = lane & 3;
        for (int c = wv; c < 20; c += 8) {
            const int R = (c << 4) + r16;
            glds16((const char*)W + ((size_t)R * kpad + k0) * 2 + q * 16,
                   (void*)&Ws[b][c << 9]);
        }
    };

    auto stage_A = [&](int seg) {
        const void* A = seg ? A2 : A1;
        const int lda  = seg ? lda2 : lda1;
        const int af16 = seg ? a2f16 : a1f16;
        const int kuse = seg ? K2use : K1use;
        const int kpad = seg ? kpad2 : kpad1;
        if (af16) {
            const int nch = kpad >> 3;
            const char* base = (const char*)A + (size_t)bm * lda * 2;
            for (int c = wv; c < nch; c += 8)
                glds16(base + (c << 10) + lane * 16, (void*)&As[c << 9]);
        } else {
            const int cpr = kpad >> 3;
            for (int idx = tid; idx < 64 * cpr; idx += 512) {
                const int row = idx / cpr;
                const int ks  = (idx - row * cpr) << 3;
                const int gmr = bm + row;
                f16x8 v = (f16x8){0, 0, 0, 0, 0, 0, 0, 0};
                if (gmr < M) {
                    const float* p = (const float*)A + (size_t)gmr * lda + ks;
#pragma unroll
                    for (int j = 0; j < 8; ++j)
                        v[j] = (ks + j < kuse) ? (f16)p[j] : (f16)0.f;
                }
                const int t = ks >> 5, kgc = (ks >> 3) & 3;
                *(f16x8*)&As[row * kpad + (t << 5) + ((kgc ^ SWK(row)) << 3)] = v;
            }
        }
    };

    // ---- prologue: A(seg0) + W(0) -> buf0 ----------------------------------
    stage_A(0);
    stage_W(0, 0);
    __syncthreads();

    for (int s = 0; s < ntot; ++s) {
        const int seg   = (s >= n1) ? 1 : 0;
        const int kpadA = seg ? kpad2 : kpad1;
        const int sl    = seg ? (s - n1) : s;
        const int b     = s & 1;
        const bool boundary = (s + 1 == n1) && (n2 != 0);
        // 1) issue next W slice FIRST (into buf b^1) — maximal in-flight window
        if (s + 1 < ntot) stage_W(s + 1, b ^ 1);
        // 2) fragments of current step (A resident; W from buf b)
        f16x8 af[2], bf[5];
#pragma unroll
        for (int r = 0; r < 2; ++r) {
            const int R = wrow + (r << 4) + lm;
            af[r] = *(const f16x8*)&As[R * kpadA + (sl << 5) + ((kg ^ SWK(R)) << 3)];
        }
#pragma unroll
        for (int c = 0; c < 5; ++c) {
            const int R = wcol + (c << 4) + lm;
            bf[c] = *(const f16x8*)&Ws[b][R * 32 + ((kg ^ SWK(R)) << 3)];
        }
        // 3) segment boundary: all waves must finish As reads before restage
        if (boundary) {
            __syncthreads();
            stage_A(1);
        }
        // 4) MFMA (16x16x32) — overlaps in-flight staging
#pragma unroll
        for (int r = 0; r < 2; ++r)
#pragma unroll
            for (int c = 0; c < 5; ++c)
                acc[r][c] = __builtin_amdgcn_mfma_f32_16x16x32_f16(
                    af[r], bf[c], acc[r][c], 0, 0, 0);
        // 5) single end-of-step barrier: drains stage(s+1) glds; also ensures
        //    Ws[b] reads done before step s+1 issues stage(s+2) into buf b.
        __syncthreads();
    }

    // epilogue: C/D frag col = lane&15, row = 4*(lane>>4)+i ; only n<300 stored
#pragma unroll
    for (int r = 0; r < 2; ++r) {
        const int gm0 = bm + wrow + (r << 4) + ((lane >> 4) << 2);
#pragma unroll
        for (int c = 0; c < 5; ++c) {
            const int n = wcol + (c << 4) + lm;
            if (n >= HID) continue;
            const float bi = bias ? bias[n] : 0.f;
#pragma unroll
            for (int i = 0; i < 4; ++i) {
                const int gmo = gm0 + i;
                if (gmo >= M) continue;
                float v = acc[r][c][i] + bi;
                if (do_relu) v = fmaxf(v, 0.f);
                C[(size_t)gmo * ldc + n] = (f16)v;
            }
        }
    }
}

// ---------------------------------------------------------------------------
// edge_csr: per target atom, accumulate messages of incoming edges in fp32
// registers, store one coalesced row. APB=8 atoms/block amortizes the
// per-block bond-weight preload. csrc/eaPk NT loads; nei NT store.
// ---------------------------------------------------------------------------
template <int NSLOTS>
__global__ __launch_bounds__(192) void edge_csr(
    const unsigned* __restrict__ xa,      // [N][150] u32 pairs
    const unsigned* __restrict__ hn0,
    const unsigned* __restrict__ hn1,
    const int* __restrict__ rowPtr,
    const int* __restrict__ csrc,
    const unsigned* __restrict__ eaPk,    // [E][7] u32 (14 f16)
    const float* __restrict__ Wi,         // [300,147] fp32 (bond cols 133..146)
    unsigned* __restrict__ out,           // nei [N][160] u32, swizzled
    int N)
{
    const int p = threadIdx.x;
    f16x2 wpk[14];
    if (p < 150) {
#pragma unroll
        for (int k = 0; k < 14; ++k)
            wpk[k] = (f16x2){(f16)Wi[(2 * p) * 147 + 133 + k],
                             (f16)Wi[(2 * p + 1) * 147 + 133 + k]};
    }
    const f16x2 zero2 = (f16x2){(f16)0.f, (f16)0.f};

    const int a0 = blockIdx.x * APB;
    const int a1 = min(a0 + APB, N);
    for (int a = a0; a < a1; ++a) {
        const int beg = rowPtr[a];
        const int end = rowPtr[a + 1];
        float acc0 = 0.f, acc1 = 0.f;
        if (p < 150) {
#pragma unroll 2
            for (int j = beg; j < end; ++j) {
                const int s = __builtin_nontemporal_load(&csrc[j]);
                const size_t srow = (size_t)s * 150 + p;
                const unsigned u0 = xa[srow];
                unsigned u1 = 0, u2 = 0;
                if (NSLOTS > 1) u1 = hn0[srow];
                if (NSLOTS > 2) u2 = hn1[srow];
                const unsigned* eq = eaPk + (size_t)j * 7;
                f16x2 ebA = zero2, ebB = zero2;
#pragma unroll
                for (int k = 0; k < 7; ++k) {
                    const f16x2 e2 = u2h(__builtin_nontemporal_load(&eq[k]));
                    ebA += (f16x2){e2.x, e2.x} * wpk[2 * k];
                    ebB += (f16x2){e2.y, e2.y} * wpk[2 * k + 1];
                }
                f16x2 m = __builtin_elementwise_max(u2h(u0) + (ebA + ebB), zero2);
                if (NSLOTS > 1) m = __builtin_elementwise_max(m + u2h(u1), zero2);
                if (NSLOTS > 2) m = __builtin_elementwise_max(m + u2h(u2), zero2);
                acc0 += (float)m.x;
                acc1 += (float)m.y;
            }
        }
        if (p < NEIP / 2) {
            const unsigned val = (p < 150) ? pk16(acc0, acc1) : 0u;
            const int t = p >> 4, kgc = (p >> 2) & 3, w = p & 3;
            __builtin_nontemporal_store(val,
                &out[(size_t)a * (NEIP / 2) + (t << 4) + ((kgc ^ SWK(a)) << 2) + w]);
        }
    }
}

// ---------------------------------------------------------------------------
// mol_pool: mol[b,:300] = sum of atom_h rows (f16, stride 300) with batch==b
// ---------------------------------------------------------------------------
__global__ __launch_bounds__(256) void mol_pool(
    const f16* __restrict__ ah,       // [N][300] f16
    const int* __restrict__ batch,    // [N], sorted
    float* __restrict__ mol,          // [B,300]
    int N)
{
    const int b = blockIdx.x;
    int lo = 0, hi = N;
    while (lo < hi) { int mid = (lo + hi) >> 1; if (batch[mid] < b) lo = mid + 1; else hi = mid; }
    const int start = lo;
    hi = N;
    while (lo < hi) { int mid = (lo + hi) >> 1; if (batch[mid] < b + 1) lo = mid + 1; else hi = mid; }
    const int end = lo;

    for (int h = threadIdx.x; h < HID; h += 256) {
        float s = 0.f;
        for (int a = start; a < end; ++a) s += (float)ah[(size_t)a * HID + h];
        mol[(size_t)b * HID + h] = s;
    }
}

// ---------------------------------------------------------------------------
__global__ __launch_bounds__(64) void ffn2_k(
    const f16* __restrict__ h1,       // [B][300] f16
    const float* __restrict__ w2,     // [300]
    const float* __restrict__ b2, float* __restrict__ out, int B)
{
    const int b = blockIdx.x;
    float s = 0.f;
    for (int k = threadIdx.x; k < HID; k += 64)
        s += (float)h1[(size_t)b * HID + k] * w2[k];
#pragma unroll
    for (int off = 32; off > 0; off >>= 1) s += __shfl_down(s, off);
    if (threadIdx.x == 0) out[b] = s + b2[0];
}

// ---------------------------------------------------------------------------
extern "C" void kernel_launch(void* const* d_in, const int* in_sizes, int n_in,
                              void* d_out, int out_size, void* d_ws, size_t ws_size,
                              hipStream_t stream)
{
    float* outp = (float*)d_out;
    const int fillBlocks = (out_size + 255) / 256;

    if (n_in < 12) {
        fill_f32<<<fillBlocks, 256, 0, stream>>>(outp, out_size, 2.0e6f + n_in);
        return;
    }

    const int N = in_sizes[0] / 133;   // atoms
    const int E = in_sizes[1] / 2;     // edges
    const int B = out_size;            // molecules

    const long long expect[12] = {
        (long long)N * 133, (long long)E * 2, (long long)E * 14, N,
        300LL * 147, 300LL * 300, 300LL * 433, 300,
        300LL * 300, 300, 300, 1 };
    for (int i = 0; i < 12; ++i) {
        if ((long long)in_sizes[i] != expect[i]) {
            fill_f32<<<fillBlocks, 256, 0, stream>>>(outp, out_size,
                                                     3.0e6f + 1.0e4f * i);
            return;
        }
    }

    const int G = (N + 1023) / 1024;   // scan blocks (N=100K -> 98)
    if (G > 1024) {
        fill_f32<<<fillBlocks, 256, 0, stream>>>(outp, out_size, 4.0e6f);
        return;
    }

    // ---- workspace layout ---------------------------------------------------
    char* basep = (char*)d_ws;
    auto align16 = [](size_t v) { return (v + 15) & ~(size_t)15; };
    const size_t slotB  = align16((size_t)N * HID * sizeof(f16));    // 60 MB
    const size_t neiB   = align16((size_t)N * NEIP * sizeof(f16));   // 64 MB
    const size_t wSmall = align16(320 * 160 * sizeof(f16));
    const size_t wBig   = align16(320 * 320 * sizeof(f16));
    const size_t molB   = align16((size_t)B * HID * sizeof(float));
    const size_t h1B    = align16((size_t)B * HID * sizeof(f16));
    const size_t rpB    = align16((size_t)(N + 1) * sizeof(int));
    const size_t curB   = align16((size_t)N * sizeof(int));
    const size_t csrcB  = align16((size_t)E * sizeof(int));
    const size_t eaB    = align16((size_t)E * 7 * sizeof(unsigned));
    const size_t bsB    = align16(1024 * sizeof(int));
    const size_t need = 3 * slotB + neiB + 2 * wSmall + 3 * wBig
                      + molB + h1B + rpB + 2 * curB + csrcB + eaB + 2 * bsB;

    if (ws_size < need) {
        fill_f32<<<fillBlocks, 256, 0, stream>>>(outp, out_size,
                                                 (float)(ws_size >> 20));
        return;
    }

    const float* x     = (const float*)d_in[0];
    const int*   ei    = (const int*)d_in[1];
    const float* ea    = (const float*)d_in[2];
    const int*   batch = (const int*)d_in[3];
    const float* W_i   = (const float*)d_in[4];
    const float* W_h   = (const float*)d_in[5];
    const float* W_o   = (const float*)d_in[6];
    const float* W_ob  = (const float*)d_in[7];
    const float* f1w   = (const float*)d_in[8];
    const float* f1b   = (const float*)d_in[9];
    const float* f2w   = (const float*)d_in[10];
    const float* f2b   = (const float*)d_in[11];
    const int* src = ei;
    const int* tgt = ei + E;

    char* cp = basep;
    f16* xa     = (f16*)cp;         cp += slotB;   // later atom_h
    f16* hn0    = (f16*)cp;         cp += slotB;
    f16* hn1    = (f16*)cp;         cp += slotB;
    f16* nei    = (f16*)cp;         cp += neiB;
    f16* WiA    = (f16*)cp;         cp += wSmall;
    f16* Wh     = (f16*)cp;         cp += wBig;
    f16* WoA    = (f16*)cp;         cp += wSmall;
    f16* WoB    = (f16*)cp;         cp += wBig;
    f16* Wf1    = (f16*)cp;         cp += wBig;
    float* mol  = (float*)cp;       cp += molB;
    f16* h1     = (f16*)cp;         cp += h1B;
    int* rowPtr = (int*)cp;         cp += rpB;
    int* cursor = (int*)cp;         cp += curB;
    int* deg    = (int*)cp;         cp += curB;
    int* csrc   = (int*)cp;         cp += csrcB;
    unsigned* eaPk = (unsigned*)cp; cp += eaB;
    int* bsum   = (int*)cp;         cp += bsB;
    int* boff   = (int*)cp;         cp += bsB;

    const unsigned* xa_u  = (const unsigned*)xa;
    const unsigned* hn0_u = (const unsigned*)hn0;
    const unsigned* hn1_u = (const unsigned*)hn1;
    unsigned*       nei_u = (unsigned*)nei;

    const int gAtom = (N + 63) / 64;      // 1563 blocks (BM=64, 512 thr)
    const int gMolG = (B + 63) / 64;
    const int gEdge = (N + APB - 1) / APB;

    // --- CSR build (+ permuted f16 bond features) ---
    zero_i32<<<128, 256, 0, stream>>>(deg, N);
    hist_tgt<<<1024, 256, 0, stream>>>(tgt, deg, E, N);
    scan_p1<<<G, 1024, 0, stream>>>(deg, bsum, N);
    scan_p2<<<1, 1024, 0, stream>>>(bsum, boff, G, rowPtr + N, E);
    scan_p3<<<G, 1024, 0, stream>>>(deg, boff, rowPtr, cursor, N);
    scatter_e<<<1024, 256, 0, stream>>>(src, tgt, ea, cursor, csrc, eaPk, E, N);

    // --- weights -> padded, pre-swizzled f16 ---
    cvt_pad_f16<<<64,  256, 0, stream>>>(WiA, W_i,       300, 147, 133, 160, 320);
    cvt_pad_f16<<<128, 256, 0, stream>>>(Wh,  W_h,       300, 300, 300, 320, 320);
    cvt_pad_f16<<<64,  256, 0, stream>>>(WoA, W_o,       300, 433, 133, 160, 320);
    cvt_pad_f16<<<128, 256, 0, stream>>>(WoB, W_o + 133, 300, 433, 300, 320, 320);
    cvt_pad_f16<<<128, 256, 0, stream>>>(Wf1, f1w,       300, 300, 300, 320, 320);

    // 1. xa = x @ W_i[:, :133]^T -> xa [N][300]
    gemm_mfma<<<gAtom, 512, 0, stream>>>(x, 133, 0, 133, WiA, 160,
        nullptr, 0, 0, 0, nullptr, 0, nullptr, xa, HID, N, 0);
    // 2. nei0 = segsum(m0)
    edge_csr<1><<<gEdge, 192, 0, stream>>>(xa_u, hn0_u, hn1_u, rowPtr, csrc,
                                           eaPk, W_i, nei_u, N);
    // 3. hn0 = nei0 @ W_h^T
    gemm_mfma<<<gAtom, 512, 0, stream>>>(nei, NEIP, 1, NEIP, Wh, 320,
        nullptr, 0, 0, 0, nullptr, 0, nullptr, hn0, HID, N, 0);
    // 4. nei1 = segsum(m1)
    edge_csr<2><<<gEdge, 192, 0, stream>>>(xa_u, hn0_u, hn1_u, rowPtr, csrc,
                                           eaPk, W_i, nei_u, N);
    // 5. hn1 = nei1 @ W_h^T
    gemm_mfma<<<gAtom, 512, 0, stream>>>(nei, NEIP, 1, NEIP, Wh, 320,
        nullptr, 0, 0, 0, nullptr, 0, nullptr, hn1, HID, N, 0);
    // 6. atom_msg = segsum(m2)
    edge_csr<3><<<gEdge, 192, 0, stream>>>(xa_u, hn0_u, hn1_u, rowPtr, csrc,
                                           eaPk, W_i, nei_u, N);
    // 7. atom_h = relu(x @ WoA^T + msg @ WoB^T + b) -> xa buffer (dead)
    gemm_mfma<<<gAtom, 512, 0, stream>>>(x, 133, 0, 133, WoA, 160,
        nei, NEIP, 1, NEIP, WoB, 320, W_ob, xa, HID, N, 1);
    // 8. mol[b] = segment_sum(atom_h)
    mol_pool<<<B, 256, 0, stream>>>(xa, batch, mol, N);
    // 9. h1 = relu(mol @ ffn1^T + b1)
    gemm_mfma<<<gMolG, 512, 0, stream>>>(mol, 300, 0, 300, Wf1, 320,
        nullptr, 0, 0, 0, nullptr, 0, f1b, h1, HID, B, 1);
    // 10. out = h1 @ ffn2^T + b2
    ffn2_k<<<B, 64, 0, stream>>>(h1, f2w, f2b, outp, B);
}

// Round 21
// 769.491 us; speedup vs baseline: 1.1704x; 1.0031x over previous
//
#include <hip/hip_runtime.h>
#include <hip/hip_fp16.h>

#define HID   300
#define NEIP  320            // nei row stride (f16), mult of 32
#define PSTR  900            // packed gather row stride in f16 (3 slots x 300)
#define APB   8              // atoms per block in edge_csr
#define SWK(r) (((r) >> 1) & 3)   // 16B sub-chunk swizzle key within 64B tile

typedef _Float16 f16;
typedef f16  f16x2 __attribute__((ext_vector_type(2)));
typedef f16  f16x8 __attribute__((ext_vector_type(8)));
typedef float f32x4 __attribute__((ext_vector_type(4)));

// ---------------------------------------------------------------------------
// helpers
// ---------------------------------------------------------------------------
__device__ __forceinline__ f16x2 u2h(unsigned u) {
    union { unsigned u; f16x2 h; } c; c.u = u; return c.h;
}
__device__ __forceinline__ unsigned pk16(float a, float b) {
    union { f16 h[2]; unsigned u; } c; c.h[0] = (f16)a; c.h[1] = (f16)b;
    return c.u;
}
__device__ __forceinline__ void glds16(const void* g, void* l) {
    __builtin_amdgcn_global_load_lds(
        (const __attribute__((address_space(1))) void*)g,
        (__attribute__((address_space(3))) void*)l, 16, 0, 0);
}

// ---------------------------------------------------------------------------
__global__ __launch_bounds__(256) void fill_f32(float* __restrict__ p, int n, float v)
{
    int i = blockIdx.x * blockDim.x + threadIdx.x;
    int stride = gridDim.x * blockDim.x;
    for (; i < n; i += stride) p[i] = v;
}

__global__ __launch_bounds__(256) void zero_i32(int* __restrict__ p, int n)
{
    int i = blockIdx.x * blockDim.x + threadIdx.x;
    int stride = gridDim.x * blockDim.x;
    for (; i < n; i += stride) p[i] = 0;
}

// dst [dstRows][kpad] f16 zero-padded, 16B-sub-chunk-swizzled within each
// 64B k-tile (so a linear global_load_lds lands it pre-swizzled in LDS).
__global__ __launch_bounds__(256) void cvt_pad_f16(
    f16* __restrict__ dst, const float* __restrict__ src,
    int srcRows, int ldsrc, int kuse, int kpad, int dstRows)
{
    int i = blockIdx.x * 256 + threadIdx.x;
    const int total = dstRows * kpad;
    const int st = gridDim.x * 256;
    for (; i < total; i += st) {
        int r = i / kpad, k = i - r * kpad;
        float v = (r < srcRows && k < kuse) ? src[(size_t)r * ldsrc + k] : 0.f;
        const int t = k >> 5, kg = (k >> 3) & 3, w = k & 7;
        const int kd = (t << 5) | ((kg ^ SWK(r)) << 3) | w;
        dst[(size_t)r * kpad + kd] = (f16)v;
    }
}

// ---------------------------------------------------------------------------
// CSR build: histogram -> hierarchical scan -> scatter (+ ea permute to f16)
// ---------------------------------------------------------------------------
__global__ __launch_bounds__(256) void hist_tgt(
    const int* __restrict__ tgt, int* __restrict__ deg, int E, int N)
{
    int e = blockIdx.x * 256 + threadIdx.x;
    const int st = gridDim.x * 256;
    for (; e < E; e += st) {
        int t = tgt[e];
        t = ((unsigned)t < (unsigned)N) ? t : 0;
        atomicAdd(&deg[t], 1);
    }
}

__global__ __launch_bounds__(1024) void scan_p1(
    const int* __restrict__ deg, int* __restrict__ bsum, int N)
{
    __shared__ int s[1024];
    const int t = threadIdx.x;
    const int i = blockIdx.x * 1024 + t;
    s[t] = (i < N) ? deg[i] : 0;
    __syncthreads();
#pragma unroll
    for (int off = 512; off > 0; off >>= 1) {
        if (t < off) s[t] += s[t + off];
        __syncthreads();
    }
    if (t == 0) bsum[blockIdx.x] = s[0];
}

__global__ __launch_bounds__(1024) void scan_p2(
    const int* __restrict__ bsum, int* __restrict__ boff,
    int G, int* __restrict__ rowPtrN, int E)
{
    __shared__ int s[1024];
    const int t = threadIdx.x;
    s[t] = (t < G) ? bsum[t] : 0;
    __syncthreads();
    for (int off = 1; off < 1024; off <<= 1) {
        const int v = (t >= off) ? s[t - off] : 0;
        __syncthreads();
        s[t] += v;
        __syncthreads();
    }
    if (t < G) boff[t] = (t == 0) ? 0 : s[t - 1];
    if (t == 0) *rowPtrN = E;
}

__global__ __launch_bounds__(1024) void scan_p3(
    const int* __restrict__ deg, const int* __restrict__ boff,
    int* __restrict__ rowPtr, int* __restrict__ cursor, int N)
{
    __shared__ int s[1024];
    const int t = threadIdx.x;
    const int i = blockIdx.x * 1024 + t;
    const int v = (i < N) ? deg[i] : 0;
    s[t] = v;
    __syncthreads();
    for (int off = 1; off < 1024; off <<= 1) {
        const int w = (t >= off) ? s[t - off] : 0;
        __syncthreads();
        s[t] += w;
        __syncthreads();
    }
    if (i < N) {
        const int excl = boff[blockIdx.x] + s[t] - v;
        rowPtr[i] = excl;
        cursor[i] = excl;
    }
}

__global__ __launch_bounds__(256) void scatter_e(
    const int* __restrict__ src, const int* __restrict__ tgt,
    const float* __restrict__ ea,
    int* __restrict__ cursor, int* __restrict__ csrc,
    unsigned* __restrict__ eaPk,    // [E][7] u32 (14 f16)
    int E, int N)
{
    int e = blockIdx.x * 256 + threadIdx.x;
    const int st = gridDim.x * 256;
    for (; e < E; e += st) {
        int t = tgt[e];
        int s = src[e];
        t = ((unsigned)t < (unsigned)N) ? t : 0;
        s = ((unsigned)s < (unsigned)N) ? s : 0;
        const int p = atomicAdd(&cursor[t], 1);
        csrc[p] = s;
        const float* er = ea + (size_t)e * 14;
        unsigned* dst = eaPk + (size_t)p * 7;
#pragma unroll
        for (int k = 0; k < 7; ++k)
            dst[k] = pk16(er[2 * k], er[2 * k + 1]);
    }
}

// ---------------------------------------------------------------------------
// MFMA GEMM, K-resident A + double-buffered W, ONE barrier per K-step
// (r20-proven config). C written with row stride ldc (slots of packed array).
// ---------------------------------------------------------------------------
__global__ __launch_bounds__(512) void gemm_mfma(
    const void* __restrict__ A1, int lda1, int a1f16, int K1use,
    const f16* __restrict__ W1, int kpad1,
    const void* __restrict__ A2, int lda2, int a2f16, int K2use,
    const f16* __restrict__ W2, int kpad2,
    const float* __restrict__ bias,
    f16* __restrict__ C, int ldc,
    int M, int do_relu)
{
    __shared__ f16 As[64 * 320];       // 40 KB resident A (current segment)
    __shared__ f16 Ws[2][320 * 32];    // 2 x 20 KB W slices

    const int tid  = threadIdx.x;
    const int bm   = blockIdx.x * 64;
    const int lane = tid & 63;
    const int wv   = tid >> 6;          // 0..7
    const int wrow = (wv >> 2) * 32;    // 0 / 32
    const int wcol = (wv & 3) * 80;     // 0/80/160/240
    const int lm   = lane & 15;
    const int kg   = lane >> 4;         // 16B sub-chunk of this lane's fragment

    const int n1 = A1 ? (kpad1 >> 5) : 0;
    const int n2 = A2 ? (kpad2 >> 5) : 0;
    const int ntot = n1 + n2;

    f32x4 acc[2][5];
#pragma unroll
    for (int r = 0; r < 2; ++r)
#pragma unroll
        for (int c = 0; c < 5; ++c) acc[r][c] = (f32x4){0.f, 0.f, 0.f, 0.f};

    auto stage_W = [&](int s, int b) {
        const f16* W = (s < n1) ? W1 : W2;
        const int kpad = (s < n1) ? kpad1 : kpad2;
        const int k0 = (((s < n1) ? s : s - n1) << 5);
        const int r16 = lane >> 2;
        const int q   = lane & 3;
        for (int c = wv; c < 20; c += 8) {
            const int R = (c << 4) + r16;
            glds16((const char*)W + ((size_t)R * kpad + k0) * 2 + q * 16,
                   (void*)&Ws[b][c << 9]);
        }
    };

    auto stage_A = [&](int seg) {
        const void* A = seg ? A2 : A1;
        const int lda  = seg ? lda2 : lda1;
        const int af16 = seg ? a2f16 : a1f16;
        const int kuse = seg ? K2use : K1use;
        const int kpad = seg ? kpad2 : kpad1;
        if (af16) {
            const int nch = kpad >> 3;
            const char* base = (const char*)A + (size_t)bm * lda * 2;
            for (int c = wv; c < nch; c += 8)
                glds16(base + (c << 10) + lane * 16, (void*)&As[c << 9]);
        } else {
            const int cpr = kpad >> 3;
            for (int idx = tid; idx < 64 * cpr; idx += 512) {
                const int row = idx / cpr;
                const int ks  = (idx - row * cpr) << 3;
                const int gmr = bm + row;
                f16x8 v = (f16x8){0, 0, 0, 0, 0, 0, 0, 0};
                if (gmr < M) {
                    const float* p = (const float*)A + (size_t)gmr * lda + ks;
#pragma unroll
                    for (int j = 0; j < 8; ++j)
                        v[j] = (ks + j < kuse) ? (f16)p[j] : (f16)0.f;
                }
                const int t = ks >> 5, kgc = (ks >> 3) & 3;
                *(f16x8*)&As[row * kpad + (t << 5) + ((kgc ^ SWK(row)) << 3)] = v;
            }
        }
    };

    // ---- prologue: A(seg0) + W(0) -> buf0 ----------------------------------
    stage_A(0);
    stage_W(0, 0);
    __syncthreads();

    for (int s = 0; s < ntot; ++s) {
        const int seg   = (s >= n1) ? 1 : 0;
        const int kpadA = seg ? kpad2 : kpad1;
        const int sl    = seg ? (s - n1) : s;
        const int b     = s & 1;
        const bool boundary = (s + 1 == n1) && (n2 != 0);
        // 1) issue next W slice FIRST (into buf b^1) — maximal in-flight window
        if (s + 1 < ntot) stage_W(s + 1, b ^ 1);
        // 2) fragments of current step (A resident; W from buf b)
        f16x8 af[2], bf[5];
#pragma unroll
        for (int r = 0; r < 2; ++r) {
            const int R = wrow + (r << 4) + lm;
            af[r] = *(const f16x8*)&As[R * kpadA + (sl << 5) + ((kg ^ SWK(R)) << 3)];
        }
#pragma unroll
        for (int c = 0; c < 5; ++c) {
            const int R = wcol + (c << 4) + lm;
            bf[c] = *(const f16x8*)&Ws[b][R * 32 + ((kg ^ SWK(R)) << 3)];
        }
        // 3) segment boundary: all waves must finish As reads before restage
        if (boundary) {
            __syncthreads();
            stage_A(1);
        }
        // 4) MFMA (16x16x32) — overlaps in-flight staging
#pragma unroll
        for (int r = 0; r < 2; ++r)
#pragma unroll
            for (int c = 0; c < 5; ++c)
                acc[r][c] = __builtin_amdgcn_mfma_f32_16x16x32_f16(
                    af[r], bf[c], acc[r][c], 0, 0, 0);
        // 5) single end-of-step barrier
        __syncthreads();
    }

    // epilogue: C/D frag col = lane&15, row = 4*(lane>>4)+i ; only n<300 stored
#pragma unroll
    for (int r = 0; r < 2; ++r) {
        const int gm0 = bm + wrow + (r << 4) + ((lane >> 4) << 2);
#pragma unroll
        for (int c = 0; c < 5; ++c) {
            const int n = wcol + (c << 4) + lm;
            if (n >= HID) continue;
            const float bi = bias ? bias[n] : 0.f;
#pragma unroll
            for (int i = 0; i < 4; ++i) {
                const int gmo = gm0 + i;
                if (gmo >= M) continue;
                float v = acc[r][c][i] + bi;
                if (do_relu) v = fmaxf(v, 0.f);
                C[(size_t)gmo * ldc + n] = (f16)v;
            }
        }
    }
}

// ---------------------------------------------------------------------------
// edge_csr: per target atom, accumulate messages of incoming edges in fp32
// registers, store one coalesced row. Gather source is the PACKED array
// [N][900] f16 (slots +0/+150/+300 u32): ONE 64-bit address per edge; the
// hn0/hn1 loads use 13-bit immediate offsets (600B / 1200B) — two 64-bit
// address chains deleted vs the 3-array layout.
// ---------------------------------------------------------------------------
template <int NSLOTS>
__global__ __launch_bounds__(192) void edge_csr(
    const unsigned* __restrict__ packed,  // [N][450] u32
    const int* __restrict__ rowPtr,
    const int* __restrict__ csrc,
    const unsigned* __restrict__ eaPk,    // [E][7] u32 (14 f16)
    const float* __restrict__ Wi,         // [300,147] fp32 (bond cols 133..146)
    unsigned* __restrict__ out,           // nei [N][160] u32, swizzled
    int N)
{
    const int p = threadIdx.x;
    f16x2 wpk[14];
    if (p < 150) {
#pragma unroll
        for (int k = 0; k < 14; ++k)
            wpk[k] = (f16x2){(f16)Wi[(2 * p) * 147 + 133 + k],
                             (f16)Wi[(2 * p + 1) * 147 + 133 + k]};
    }
    const f16x2 zero2 = (f16x2){(f16)0.f, (f16)0.f};

    const int a0 = blockIdx.x * APB;
    const int a1 = min(a0 + APB, N);
    for (int a = a0; a < a1; ++a) {
        const int beg = rowPtr[a];
        const int end = rowPtr[a + 1];
        float acc0 = 0.f, acc1 = 0.f;
        if (p < 150) {
#pragma unroll 2
            for (int j = beg; j < end; ++j) {
                const int s = __builtin_nontemporal_load(&csrc[j]);
                const unsigned* row = packed + (size_t)s * (PSTR / 2) + p;
                const unsigned u0 = row[0];
                unsigned u1 = 0, u2 = 0;
                if (NSLOTS > 1) u1 = row[150];   // +600B imm offset
                if (NSLOTS > 2) u2 = row[300];   // +1200B imm offset
                const unsigned* eq = eaPk + (size_t)j * 7;
                f16x2 ebA = zero2, ebB = zero2;
#pragma unroll
                for (int k = 0; k < 7; ++k) {
                    const f16x2 e2 = u2h(__builtin_nontemporal_load(&eq[k]));
                    ebA += (f16x2){e2.x, e2.x} * wpk[2 * k];
                    ebB += (f16x2){e2.y, e2.y} * wpk[2 * k + 1];
                }
                f16x2 m = __builtin_elementwise_max(u2h(u0) + (ebA + ebB), zero2);
                if (NSLOTS > 1) m = __builtin_elementwise_max(m + u2h(u1), zero2);
                if (NSLOTS > 2) m = __builtin_elementwise_max(m + u2h(u2), zero2);
                acc0 += (float)m.x;
                acc1 += (float)m.y;
            }
        }
        if (p < NEIP / 2) {
            const unsigned val = (p < 150) ? pk16(acc0, acc1) : 0u;
            const int t = p >> 4, kgc = (p >> 2) & 3, w = p & 3;
            __builtin_nontemporal_store(val,
                &out[(size_t)a * (NEIP / 2) + (t << 4) + ((kgc ^ SWK(a)) << 2) + w]);
        }
    }
}

// ---------------------------------------------------------------------------
// mol_pool: mol[b,:300] = sum of atom_h rows (f16, stride PSTR) with batch==b
// ---------------------------------------------------------------------------
__global__ __launch_bounds__(256) void mol_pool(
    const f16* __restrict__ ah,       // packed slot0: [N] rows stride 900
    const int* __restrict__ batch,    // [N], sorted
    float* __restrict__ mol,          // [B,300]
    int N)
{
    const int b = blockIdx.x;
    int lo = 0, hi = N;
    while (lo < hi) { int mid = (lo + hi) >> 1; if (batch[mid] < b) lo = mid + 1; else hi = mid; }
    const int start = lo;
    hi = N;
    while (lo < hi) { int mid = (lo + hi) >> 1; if (batch[mid] < b + 1) lo = mid + 1; else hi = mid; }
    const int end = lo;

    for (int h = threadIdx.x; h < HID; h += 256) {
        float s = 0.f;
        for (int a = start; a < end; ++a) s += (float)ah[(size_t)a * PSTR + h];
        mol[(size_t)b * HID + h] = s;
    }
}

// ---------------------------------------------------------------------------
__global__ __launch_bounds__(64) void ffn2_k(
    const f16* __restrict__ h1,       // [B][300] f16
    const float* __restrict__ w2,     // [300]
    const float* __restrict__ b2, float* __restrict__ out, int B)
{
    const int b = blockIdx.x;
    float s = 0.f;
    for (int k = threadIdx.x; k < HID; k += 64)
        s += (float)h1[(size_t)b * HID + k] * w2[k];
#pragma unroll
    for (int off = 32; off > 0; off >>= 1) s += __shfl_down(s, off);
    if (threadIdx.x == 0) out[b] = s + b2[0];
}

// ---------------------------------------------------------------------------
extern "C" void kernel_launch(void* const* d_in, const int* in_sizes, int n_in,
                              void* d_out, int out_size, void* d_ws, size_t ws_size,
                              hipStream_t stream)
{
    float* outp = (float*)d_out;
    const int fillBlocks = (out_size + 255) / 256;

    if (n_in < 12) {
        fill_f32<<<fillBlocks, 256, 0, stream>>>(outp, out_size, 2.0e6f + n_in);
        return;
    }

    const int N = in_sizes[0] / 133;   // atoms
    const int E = in_sizes[1] / 2;     // edges
    const int B = out_size;            // molecules

    const long long expect[12] = {
        (long long)N * 133, (long long)E * 2, (long long)E * 14, N,
        300LL * 147, 300LL * 300, 300LL * 433, 300,
        300LL * 300, 300, 300, 1 };
    for (int i = 0; i < 12; ++i) {
        if ((long long)in_sizes[i] != expect[i]) {
            fill_f32<<<fillBlocks, 256, 0, stream>>>(outp, out_size,
                                                     3.0e6f + 1.0e4f * i);
            return;
        }
    }

    const int G = (N + 1023) / 1024;   // scan blocks (N=100K -> 98)
    if (G > 1024) {
        fill_f32<<<fillBlocks, 256, 0, stream>>>(outp, out_size, 4.0e6f);
        return;
    }

    // ---- workspace layout ---------------------------------------------------
    char* basep = (char*)d_ws;
    auto align16 = [](size_t v) { return (v + 15) & ~(size_t)15; };
    const size_t packedB = align16((size_t)N * PSTR * sizeof(f16));   // 180 MB
    const size_t neiB    = align16((size_t)N * NEIP * sizeof(f16));   // 64 MB
    const size_t wSmall  = align16(320 * 160 * sizeof(f16));
    const size_t wBig    = align16(320 * 320 * sizeof(f16));
    const size_t molB    = align16((size_t)B * HID * sizeof(float));
    const size_t h1B     = align16((size_t)B * HID * sizeof(f16));
    const size_t rpB     = align16((size_t)(N + 1) * sizeof(int));
    const size_t curB    = align16((size_t)N * sizeof(int));
    const size_t csrcB   = align16((size_t)E * sizeof(int));
    const size_t eaB     = align16((size_t)E * 7 * sizeof(unsigned));
    const size_t bsB     = align16(1024 * sizeof(int));
    const size_t need = packedB + neiB + 2 * wSmall + 3 * wBig
                      + molB + h1B + rpB + 2 * curB + csrcB + eaB + 2 * bsB;

    if (ws_size < need) {
        fill_f32<<<fillBlocks, 256, 0, stream>>>(outp, out_size,
                                                 (float)(ws_size >> 20));
        return;
    }

    const float* x     = (const float*)d_in[0];
    const int*   ei    = (const int*)d_in[1];
    const float* ea    = (const float*)d_in[2];
    const int*   batch = (const int*)d_in[3];
    const float* W_i   = (const float*)d_in[4];
    const float* W_h   = (const float*)d_in[5];
    const float* W_o   = (const float*)d_in[6];
    const float* W_ob  = (const float*)d_in[7];
    const float* f1w   = (const float*)d_in[8];
    const float* f1b   = (const float*)d_in[9];
    const float* f2w   = (const float*)d_in[10];
    const float* f2b   = (const float*)d_in[11];
    const int* src = ei;
    const int* tgt = ei + E;

    char* cp = basep;
    f16* packed = (f16*)cp;        cp += packedB;
    f16* nei    = (f16*)cp;        cp += neiB;
    f16* WiA    = (f16*)cp;        cp += wSmall;
    f16* Wh     = (f16*)cp;        cp += wBig;
    f16* WoA    = (f16*)cp;        cp += wSmall;
    f16* WoB    = (f16*)cp;        cp += wBig;
    f16* Wf1    = (f16*)cp;        cp += wBig;
    float* mol  = (float*)cp;      cp += molB;
    f16* h1     = (f16*)cp;        cp += h1B;
    int* rowPtr = (int*)cp;        cp += rpB;
    int* cursor = (int*)cp;        cp += curB;
    int* deg    = (int*)cp;        cp += curB;
    int* csrc   = (int*)cp;        cp += csrcB;
    unsigned* eaPk = (unsigned*)cp; cp += eaB;
    int* bsum   = (int*)cp;        cp += bsB;
    int* boff   = (int*)cp;        cp += bsB;

    f16* xa_s  = packed;          // slot 0 (later atom_h)
    f16* hn0_s = packed + 300;    // slot 1
    f16* hn1_s = packed + 600;    // slot 2

    const unsigned* packed_u = (const unsigned*)packed;
    unsigned*       nei_u    = (unsigned*)nei;

    const int gAtom = (N + 63) / 64;      // 1563 blocks (BM=64, 512 thr)
    const int gMolG = (B + 63) / 64;
    const int gEdge = (N + APB - 1) / APB;

    // --- CSR build (+ permuted f16 bond features) ---
    zero_i32<<<128, 256, 0, stream>>>(deg, N);
    hist_tgt<<<1024, 256, 0, stream>>>(tgt, deg, E, N);
    scan_p1<<<G, 1024, 0, stream>>>(deg, bsum, N);
    scan_p2<<<1, 1024, 0, stream>>>(bsum, boff, G, rowPtr + N, E);
    scan_p3<<<G, 1024, 0, stream>>>(deg, boff, rowPtr, cursor, N);
    scatter_e<<<1024, 256, 0, stream>>>(src, tgt, ea, cursor, csrc, eaPk, E, N);

    // --- weights -> padded, pre-swizzled f16 ---
    cvt_pad_f16<<<64,  256, 0, stream>>>(WiA, W_i,       300, 147, 133, 160, 320);
    cvt_pad_f16<<<128, 256, 0, stream>>>(Wh,  W_h,       300, 300, 300, 320, 320);
    cvt_pad_f16<<<64,  256, 0, stream>>>(WoA, W_o,       300, 433, 133, 160, 320);
    cvt_pad_f16<<<128, 256, 0, stream>>>(WoB, W_o + 133, 300, 433, 300, 320, 320);
    cvt_pad_f16<<<128, 256, 0, stream>>>(Wf1, f1w,       300, 300, 300, 320, 320);

    // 1. xa = x @ W_i[:, :133]^T -> packed slot0
    gemm_mfma<<<gAtom, 512, 0, stream>>>(x, 133, 0, 133, WiA, 160,
        nullptr, 0, 0, 0, nullptr, 0, nullptr, xa_s, PSTR, N, 0);
    // 2. nei0 = segsum(m0)
    edge_csr<1><<<gEdge, 192, 0, stream>>>(packed_u, rowPtr, csrc, eaPk, W_i,
                                           nei_u, N);
    // 3. hn0 = nei0 @ W_h^T -> packed slot1
    gemm_mfma<<<gAtom, 512, 0, stream>>>(nei, NEIP, 1, NEIP, Wh, 320,
        nullptr, 0, 0, 0, nullptr, 0, nullptr, hn0_s, PSTR, N, 0);
    // 4. nei1 = segsum(m1)
    edge_csr<2><<<gEdge, 192, 0, stream>>>(packed_u, rowPtr, csrc, eaPk, W_i,
                                           nei_u, N);
    // 5. hn1 = nei1 @ W_h^T -> packed slot2
    gemm_mfma<<<gAtom, 512, 0, stream>>>(nei, NEIP, 1, NEIP, Wh, 320,
        nullptr, 0, 0, 0, nullptr, 0, nullptr, hn1_s, PSTR, N, 0);
    // 6. atom_msg = segsum(m2)
    edge_csr<3><<<gEdge, 192, 0, stream>>>(packed_u, rowPtr, csrc, eaPk, W_i,
                                           nei_u, N);
    // 7. atom_h = relu(x @ WoA^T + msg @ WoB^T + b) -> packed slot0 (xa dead)
    gemm_mfma<<<gAtom, 512, 0, stream>>>(x, 133, 0, 133, WoA, 160,
        nei, NEIP, 1, NEIP, WoB, 320, W_ob, xa_s, PSTR, N, 1);
    // 8. mol[b] = segment_sum(atom_h)
    mol_pool<<<B, 256, 0, stream>>>(xa_s, batch, mol, N);
    // 9. h1 = relu(mol @ ffn1^T + b1)
    gemm_mfma<<<gMolG, 512, 0, stream>>>(mol, 300, 0, 300, Wf1, 320,
        nullptr, 0, 0, 0, nullptr, 0, f1b, h1, HID, B, 1);
    // 10. out = h1 @ ffn2^T + b2
    ffn2_k<<<B, 64, 0, stream>>>(h1, f2w, f2b, outp, B);
}